// Round 25
// baseline (32.214 us; speedup 1.0000x reference)
//
#include <hip/hip_runtime.h>
#include <stdint.h>

typedef __fp16    half2v __attribute__((ext_vector_type(2)));
typedef _Float16  f16x8  __attribute__((ext_vector_type(8)));
typedef float     f32x4  __attribute__((ext_vector_type(4)));
typedef uint32_t  u32x4  __attribute__((ext_vector_type(4)));

#define KSZ    5
#define NBATCH 16
#define NC     3
#define NH     256
#define NW     256
#define TW     16
#define TH     16
#define TROWS  20
#define TWRD   12               // u32 words per tile row (24 f16 cols)
#define CPLANE (TROWS * TWRD)   // 240
#define COPYW  (NC * CPLANE)    // 720
#define PTS    20               // pbuf per-pixel stride in words (16B-aligned)
#define NUNIT  (COPYW / 2)      // 360 word-pair staging units

__device__ __forceinline__ uint32_t pack_f16x2(float lo, float hi) {
    half2v h = __builtin_amdgcn_cvt_pkrtz(lo, hi);
    return __builtin_bit_cast(uint32_t, h);
}

// SHARED slot->pair map (r7-VERIFIED): k-slot (s, dword d) holds tap-pair P,
// halves = taps (i, 2q), (i, 2q+1), P = i*3+q.
__device__ __forceinline__ int pair_of(int s, int d) {
    return (d < 2) ? (2 * s + d) : (8 + 2 * s + (d - 2));
}

// r7-VERIFIED prep: virtual filters vf = i*6+jj (jj<5 -> f=i*5+jj, else pad).
__global__ void prep_AB(const float* __restrict__ cw, const float* __restrict__ cb,
                        uint32_t* __restrict__ Atab, float* __restrict__ cbv)
{
    int idx = threadIdx.x + blockIdx.x * 256;
    if (idx < 1536) {
        int d  = idx & 3;
        int fl = (idx >> 2) & 15;
        int s  = (idx >> 6) & 3;
        int t3 = idx >> 8;            // 0..5
        int c  = t3 % 3, mt = t3 / 3;
        int vf = mt * 16 + fl;
        int P  = pair_of(s, d);
        float lo = 0.0f, hi = 0.0f;
        if (vf < 30 && (vf % 6) != 5 && P < 15) {
            int f = (vf / 6) * 5 + (vf % 6);
            int i = P / 3, q = P - 3 * i;
            const float* base = cw + f * 75 + c * 25 + i * 5;
            lo = base[2 * q];
            if (q < 2) hi = base[2 * q + 1];
        }
        Atab[idx] = pack_f16x2(lo, hi);
    } else if (idx < 1568) {
        int vf = idx - 1536;
        float v = 0.0f;
        if (vf < 30 && (vf % 6) != 5) v = cb[(vf / 6) * 5 + (vf % 6)];
        cbv[vf] = v;
    }
}

__global__ __launch_bounds__(256, 5)
void highorder25(const float* __restrict__ x,
                 const uint32_t* __restrict__ Atab,
                 const float* __restrict__ cbv,
                 float* __restrict__ out)
{
    __shared__ uint32_t ldsA[2 * COPYW];         // 5760 B tile, batch b0
    __shared__ uint32_t ldsB[2 * COPYW];         // 5760 B tile, batch b0+1
    __shared__ uint32_t pbuf[TH * 16 * PTS];     // 20480 B shared sequentially

    const int tid = threadIdx.x;
    const int l   = tid & 63;
    const int w   = tid >> 6;
    const int fl  = l & 15;     // A row (vf) / B col (pixel col)
    const int s   = l >> 4;     // k-slice / D row group

    const int bx  = blockIdx.x & 15;
    const int by  = (blockIdx.x >> 4) & 15;
    const int bp  = blockIdx.x >> 8;          // 0..7
    const int b0  = bp * 2;
    const int bw0 = bx * TW;
    const int bh0 = by * TH;
    const size_t bstride = (size_t)NC * NH * NW;

    const float* xb0 = x + (size_t)b0 * bstride;
    const float* xb1 = xb0 + bstride;

    // A-fragments (weights) + bias (r7-verified) — amortized over 2 tiles
    u32x4 afr[6];
    const u32x4* At4 = (const u32x4*)Atab;
    #pragma unroll
    for (int t3 = 0; t3 < 6; ++t3)
        afr[t3] = At4[(t3 * 4 + s) * 16 + fl];
    const f32x4* cbv4 = (const f32x4*)cbv;
    const f32x4 cbA = cbv4[s];       // rows vf = 4s+r
    const f32x4 cbB = cbv4[4 + s];   // rows vf = 16+4s+r

    // ---- Stage BOTH tiles upfront (r17-verified values; loads for both
    // batches issue in one window -> 2x memory-level parallelism, no
    // registers held across compute phases)
    #pragma unroll
    for (int it = 0; it < 2; ++it) {
        int u = tid + it * 256;
        if (u < NUNIT) {
            int c   = u / 120;            // CPLANE/2
            int rem = u - c * 120;
            int r   = rem / 6;
            int j   = rem - r * 6;
            int gh  = bh0 + r - 2;
            int g0  = bw0 + 4 * j - 2;
            bool rowok = (unsigned)gh < NH;
            const int roff = c * NH * NW + (rowok ? gh : 0) * NW;
            const float* rowp0 = xb0 + roff;
            const float* rowp1 = xb1 + roff;
            float x0, x1, x2, x3, x4, y0, y1, y2, y3, y4;
            if (rowok && g0 >= 0 && g0 + 4 < NW) {
                f32x4 v0 = *reinterpret_cast<const f32x4*>(rowp0 + g0);
                f32x4 v1 = *reinterpret_cast<const f32x4*>(rowp1 + g0);
                x0 = v0[0]; x1 = v0[1]; x2 = v0[2]; x3 = v0[3];
                x4 = rowp0[g0 + 4];
                y0 = v1[0]; y1 = v1[1]; y2 = v1[2]; y3 = v1[3];
                y4 = rowp1[g0 + 4];
            } else {
                bool k0 = rowok && (unsigned)(g0)     < NW;
                bool k1 = rowok && (unsigned)(g0 + 1) < NW;
                bool k2 = rowok && (unsigned)(g0 + 2) < NW;
                bool k3 = rowok && (unsigned)(g0 + 3) < NW;
                bool k4 = rowok && (unsigned)(g0 + 4) < NW;
                x0 = k0 ? rowp0[g0]     : 0.0f;  y0 = k0 ? rowp1[g0]     : 0.0f;
                x1 = k1 ? rowp0[g0 + 1] : 0.0f;  y1 = k1 ? rowp1[g0 + 1] : 0.0f;
                x2 = k2 ? rowp0[g0 + 2] : 0.0f;  y2 = k2 ? rowp1[g0 + 2] : 0.0f;
                x3 = k3 ? rowp0[g0 + 3] : 0.0f;  y3 = k3 ? rowp1[g0 + 3] : 0.0f;
                x4 = k4 ? rowp0[g0 + 4] : 0.0f;  y4 = k4 ? rowp1[g0 + 4] : 0.0f;
            }
            const int idx0 = 2 * u;       // even -> 8B aligned
            uint2 wa; wa.x = pack_f16x2(x0, x1); wa.y = pack_f16x2(x2, x3);
            uint2 wb; wb.x = pack_f16x2(x1, x2); wb.y = pack_f16x2(x3, x4);
            *reinterpret_cast<uint2*>(&ldsA[idx0])         = wa;
            *reinterpret_cast<uint2*>(&ldsA[COPYW + idx0]) = wb;
            uint2 wc; wc.x = pack_f16x2(y0, y1); wc.y = pack_f16x2(y2, y3);
            uint2 wd; wd.x = pack_f16x2(y1, y2); wd.y = pack_f16x2(y3, y4);
            *reinterpret_cast<uint2*>(&ldsB[idx0])         = wc;
            *reinterpret_cast<uint2*>(&ldsB[COPYW + idx0]) = wd;
        }
    }
    __syncthreads();

    // per-lane word offsets for pairs pair_of(s,d); P==15 -> clamp (its weight
    // pair wq3@s==3 is exactly zero, so the term is never consumed)
    int woff[4];
    #pragma unroll
    for (int d = 0; d < 4; ++d) {
        int P = pair_of(s, d);
        int i = P / 3, q = P - 3 * i;
        woff[d] = (P == 15) ? 0 : (i * TWRD + q);
    }
    const int abase = ((fl & 1) ? COPYW : 0) + (fl >> 1);
    const int px  = tid & 15;
    const int py2 = tid >> 4;
    const int rb  = (py2 * 16 + px) * PTS;

    // ================= TILE 0 (batch b0) =================
    #pragma unroll
    for (int g = 0; g < 4; ++g) {
        const int py = w * 4 + g;
        const int bg = abase + py * TWRD;

        u32x4 bv[3];
        #pragma unroll
        for (int c = 0; c < 3; ++c)
            #pragma unroll
            for (int d = 0; d < 4; ++d)
                bv[c][d] = ldsA[bg + c * CPLANE + woff[d]];

        f32x4 a0 = cbA, a1 = cbB;
        #pragma unroll
        for (int c = 0; c < 3; ++c) {
            f16x8 B = __builtin_bit_cast(f16x8, bv[c]);
            a0 = __builtin_amdgcn_mfma_f32_16x16x32_f16(
                     __builtin_bit_cast(f16x8, afr[c]),     B, a0, 0, 0, 0);
            a1 = __builtin_amdgcn_mfma_f32_16x16x32_f16(
                     __builtin_bit_cast(f16x8, afr[3 + c]), B, a1, 0, 0, 0);
        }

        uint32_t wq0 = pack_f16x2(a0[0], a0[1]);
        uint32_t wq1 = pack_f16x2(a0[2], a0[3]);
        uint32_t wq2 = pack_f16x2(a1[0], a1[1]);
        uint32_t wq3 = pack_f16x2(a1[2], a1[3]);

        const int pb = (py * 16 + fl) * PTS;
        uint2 w01; w01.x = wq0; w01.y = wq1;
        uint2 w23; w23.x = wq2; w23.y = wq3;
        *reinterpret_cast<uint2*>(&pbuf[pb + 2 * s])     = w01;
        *reinterpret_cast<uint2*>(&pbuf[pb + 8 + 2 * s]) = w23;
    }

    uint32_t nb[45];
    {
        const uint32_t* basep = ldsA + ((px & 1) ? COPYW : 0) + (px >> 1);
        #pragma unroll
        for (int c = 0; c < NC; ++c)
            #pragma unroll
            for (int i = 0; i < KSZ; ++i)
                #pragma unroll
                for (int q = 0; q < 3; ++q)
                    nb[c * 15 + i * 3 + q] =
                        basep[c * CPLANE + (py2 + i) * TWRD + q];
    }
    __syncthreads();                 // pbuf(tile0) ready

    u32x4 wp4[4];
    #pragma unroll
    for (int r = 0; r < 4; ++r)
        wp4[r] = *reinterpret_cast<const u32x4*>(&pbuf[rb + 4 * r]);
    __syncthreads();                 // pbuf freed for tile 1

    {
        float* ob = out + (size_t)b0 * bstride
                        + (size_t)(bh0 + py2) * NW + (bw0 + px);
        #pragma unroll
        for (int c = 0; c < NC; ++c) {
            uint32_t accA = nb[c * 15 + 7] & 0xFFFFu;   // residual (ctr, 0)
            uint32_t accB = 0u;
            #pragma unroll
            for (int t = 0; t < 8; ++t)
                asm("v_pk_fma_f16 %0, %1, %2, %0"
                    : "+v"(accA)
                    : "v"(wp4[t >> 2][t & 3]), "v"(nb[c * 15 + t]));
            #pragma unroll
            for (int t = 8; t < 15; ++t)
                asm("v_pk_fma_f16 %0, %1, %2, %0"
                    : "+v"(accB)
                    : "v"(wp4[t >> 2][t & 3]), "v"(nb[c * 15 + t]));
            half2v hA = __builtin_bit_cast(half2v, accA);
            half2v hB = __builtin_bit_cast(half2v, accB);
            ob[(size_t)c * NH * NW] =
                ((float)hA.x + (float)hA.y) + ((float)hB.x + (float)hB.y);
        }
    }

    // ================= TILE 1 (batch b0+1) =================
    #pragma unroll
    for (int g = 0; g < 4; ++g) {
        const int py = w * 4 + g;
        const int bg = abase + py * TWRD;

        u32x4 bv[3];
        #pragma unroll
        for (int c = 0; c < 3; ++c)
            #pragma unroll
            for (int d = 0; d < 4; ++d)
                bv[c][d] = ldsB[bg + c * CPLANE + woff[d]];

        f32x4 a0 = cbA, a1 = cbB;
        #pragma unroll
        for (int c = 0; c < 3; ++c) {
            f16x8 B = __builtin_bit_cast(f16x8, bv[c]);
            a0 = __builtin_amdgcn_mfma_f32_16x16x32_f16(
                     __builtin_bit_cast(f16x8, afr[c]),     B, a0, 0, 0, 0);
            a1 = __builtin_amdgcn_mfma_f32_16x16x32_f16(
                     __builtin_bit_cast(f16x8, afr[3 + c]), B, a1, 0, 0, 0);
        }

        uint32_t wq0 = pack_f16x2(a0[0], a0[1]);
        uint32_t wq1 = pack_f16x2(a0[2], a0[3]);
        uint32_t wq2 = pack_f16x2(a1[0], a1[1]);
        uint32_t wq3 = pack_f16x2(a1[2], a1[3]);

        const int pb = (py * 16 + fl) * PTS;
        uint2 w01; w01.x = wq0; w01.y = wq1;
        uint2 w23; w23.x = wq2; w23.y = wq3;
        *reinterpret_cast<uint2*>(&pbuf[pb + 2 * s])     = w01;
        *reinterpret_cast<uint2*>(&pbuf[pb + 8 + 2 * s]) = w23;
    }

    {
        const uint32_t* basep = ldsB + ((px & 1) ? COPYW : 0) + (px >> 1);
        #pragma unroll
        for (int c = 0; c < NC; ++c)
            #pragma unroll
            for (int i = 0; i < KSZ; ++i)
                #pragma unroll
                for (int q = 0; q < 3; ++q)
                    nb[c * 15 + i * 3 + q] =
                        basep[c * CPLANE + (py2 + i) * TWRD + q];
    }
    __syncthreads();                 // pbuf(tile1) ready

    #pragma unroll
    for (int r = 0; r < 4; ++r)
        wp4[r] = *reinterpret_cast<const u32x4*>(&pbuf[rb + 4 * r]);

    {
        float* ob = out + (size_t)(b0 + 1) * bstride
                        + (size_t)(bh0 + py2) * NW + (bw0 + px);
        #pragma unroll
        for (int c = 0; c < NC; ++c) {
            uint32_t accA = nb[c * 15 + 7] & 0xFFFFu;   // residual (ctr, 0)
            uint32_t accB = 0u;
            #pragma unroll
            for (int t = 0; t < 8; ++t)
                asm("v_pk_fma_f16 %0, %1, %2, %0"
                    : "+v"(accA)
                    : "v"(wp4[t >> 2][t & 3]), "v"(nb[c * 15 + t]));
            #pragma unroll
            for (int t = 8; t < 15; ++t)
                asm("v_pk_fma_f16 %0, %1, %2, %0"
                    : "+v"(accB)
                    : "v"(wp4[t >> 2][t & 3]), "v"(nb[c * 15 + t]));
            half2v hA = __builtin_bit_cast(half2v, accA);
            half2v hB = __builtin_bit_cast(half2v, accB);
            ob[(size_t)c * NH * NW] =
                ((float)hA.x + (float)hA.y) + ((float)hB.x + (float)hB.y);
        }
    }
}

extern "C" void kernel_launch(void* const* d_in, const int* in_sizes, int n_in,
                              void* d_out, int out_size, void* d_ws, size_t ws_size,
                              hipStream_t stream)
{
    const float* x  = (const float*)d_in[0];
    const float* cw = (const float*)d_in[1];
    const float* cb = (const float*)d_in[2];
    float* out      = (float*)d_out;
    uint32_t* Atab  = (uint32_t*)d_ws;                    // 6144 B
    float*    cbv   = (float*)((char*)d_ws + 6144);       // 128 B

    prep_AB<<<7, 256, 0, stream>>>(cw, cb, Atab, cbv);

    dim3 grid((NH / TH) * (NW / TW) * (NBATCH / 2));   // 16*16*8 = 2048 blocks
    highorder25<<<grid, 256, 0, stream>>>(x, Atab, cbv, out);
}

// Round 26
// 27.891 us; speedup vs baseline: 1.1550x; 1.1550x over previous
//
#include <hip/hip_runtime.h>
#include <stdint.h>

typedef __fp16    half2v __attribute__((ext_vector_type(2)));
typedef _Float16  f16x8  __attribute__((ext_vector_type(8)));
typedef float     f32x4  __attribute__((ext_vector_type(4)));
typedef uint32_t  u32x4  __attribute__((ext_vector_type(4)));

#define KSZ    5
#define NBATCH 16
#define NC     3
#define NH     256
#define NW     256
#define TW     16
#define TH     16
#define TROWS  20
#define TWRD   12               // u32 words per tile row (24 f16 cols)
#define CPLANE (TROWS * TWRD)   // 240
#define COPYW  (NC * CPLANE)    // 720
#define PTS    20               // pbuf per-pixel stride in words (16B-aligned)
#define NUNIT  (COPYW / 2)      // 360 word-pair staging units

__device__ __forceinline__ uint32_t pack_f16x2(float lo, float hi) {
    half2v h = __builtin_amdgcn_cvt_pkrtz(lo, hi);
    return __builtin_bit_cast(uint32_t, h);
}

// SHARED slot->pair map (r7-VERIFIED): k-slot (s, dword d) holds tap-pair P,
// halves = taps (i, 2q), (i, 2q+1), P = i*3+q.
__device__ __forceinline__ int pair_of(int s, int d) {
    return (d < 2) ? (2 * s + d) : (8 + 2 * s + (d - 2));
}

// r7-VERIFIED prep: virtual filters vf = i*6+jj (jj<5 -> f=i*5+jj, else pad).
__global__ void prep_AB(const float* __restrict__ cw, const float* __restrict__ cb,
                        uint32_t* __restrict__ Atab, float* __restrict__ cbv)
{
    int idx = threadIdx.x + blockIdx.x * 256;
    if (idx < 1536) {
        int d  = idx & 3;
        int fl = (idx >> 2) & 15;
        int s  = (idx >> 6) & 3;
        int t3 = idx >> 8;            // 0..5
        int c  = t3 % 3, mt = t3 / 3;
        int vf = mt * 16 + fl;
        int P  = pair_of(s, d);
        float lo = 0.0f, hi = 0.0f;
        if (vf < 30 && (vf % 6) != 5 && P < 15) {
            int f = (vf / 6) * 5 + (vf % 6);
            int i = P / 3, q = P - 3 * i;
            const float* base = cw + f * 75 + c * 25 + i * 5;
            lo = base[2 * q];
            if (q < 2) hi = base[2 * q + 1];
        }
        Atab[idx] = pack_f16x2(lo, hi);
    } else if (idx < 1568) {
        int vf = idx - 1536;
        float v = 0.0f;
        if (vf < 30 && (vf % 6) != 5) v = cb[(vf / 6) * 5 + (vf % 6)];
        cbv[vf] = v;
    }
}

__global__ __launch_bounds__(256, 4)
void highorder24(const float* __restrict__ x,
                 const uint32_t* __restrict__ Atab,
                 const float* __restrict__ cbv,
                 float* __restrict__ out)
{
    __shared__ uint32_t lds_t[2 * COPYW];        // 5760 B dual-copy tile
    __shared__ uint32_t pbuf[TH * 16 * PTS];     // 20480 B [py][px][t(20)]

    const int tid = threadIdx.x;
    const int l   = tid & 63;
    const int w   = tid >> 6;
    const int fl  = l & 15;     // A row (vf) / B col (pixel col)
    const int s   = l >> 4;     // k-slice / D row group

    const int bx  = blockIdx.x & 15;
    const int by  = (blockIdx.x >> 4) & 15;
    const int b   = blockIdx.x >> 8;
    const int bw0 = bx * TW;
    const int bh0 = by * TH;

    const float* xb = x + (size_t)b * NC * NH * NW;

    // A-fragments (weights) + bias (r7-verified)
    u32x4 afr[6];
    const u32x4* At4 = (const u32x4*)Atab;
    #pragma unroll
    for (int t3 = 0; t3 < 6; ++t3)
        afr[t3] = At4[(t3 * 4 + s) * 16 + fl];
    const f32x4* cbv4 = (const f32x4*)cbv;
    const f32x4 cbA = cbv4[s];       // rows vf = 4s+r
    const f32x4 cbB = cbv4[4 + s];   // rows vf = 16+4s+r

    // ---- Staging, vectorized producer (r17-verified verbatim)
    #pragma unroll
    for (int it = 0; it < 2; ++it) {
        int u = tid + it * 256;
        if (u < NUNIT) {
            int c   = u / 120;            // CPLANE/2
            int rem = u - c * 120;
            int r   = rem / 6;
            int j   = rem - r * 6;
            int gh  = bh0 + r - 2;
            int g0  = bw0 + 4 * j - 2;
            bool rowok = (unsigned)gh < NH;
            const float* row = xb + c * NH * NW + gh * NW;
            float x0, x1, x2, x3, x4;
            if (rowok && g0 >= 0 && g0 + 4 < NW) {
                f32x4 v = *reinterpret_cast<const f32x4*>(row + g0);
                x0 = v[0]; x1 = v[1]; x2 = v[2]; x3 = v[3];
                x4 = row[g0 + 4];
            } else {
                x0 = (rowok && (unsigned)(g0)     < NW) ? row[g0]     : 0.0f;
                x1 = (rowok && (unsigned)(g0 + 1) < NW) ? row[g0 + 1] : 0.0f;
                x2 = (rowok && (unsigned)(g0 + 2) < NW) ? row[g0 + 2] : 0.0f;
                x3 = (rowok && (unsigned)(g0 + 3) < NW) ? row[g0 + 3] : 0.0f;
                x4 = (rowok && (unsigned)(g0 + 4) < NW) ? row[g0 + 4] : 0.0f;
            }
            const int idx0 = 2 * u;       // even -> 8B aligned
            uint2 wa; wa.x = pack_f16x2(x0, x1); wa.y = pack_f16x2(x2, x3);
            uint2 wb; wb.x = pack_f16x2(x1, x2); wb.y = pack_f16x2(x3, x4);
            *reinterpret_cast<uint2*>(&lds_t[idx0])         = wa;
            *reinterpret_cast<uint2*>(&lds_t[COPYW + idx0]) = wb;
        }
    }
    __syncthreads();

    // per-lane word offsets for pairs pair_of(s,d); P==15 -> clamp (its weight
    // pair wq3@s==3 is exactly zero, so the term is never consumed)
    int woff[4];
    #pragma unroll
    for (int d = 0; d < 4; ++d) {
        int P = pair_of(s, d);
        int i = P / 3, q = P - 3 * i;
        woff[d] = (P == 15) ? 0 : (i * TWRD + q);
    }
    const int abase = ((fl & 1) ? COPYW : 0) + (fl >> 1);

    #pragma unroll
    for (int g = 0; g < 4; ++g) {
        const int py = w * 4 + g;
        const int bg = abase + py * TWRD;

        u32x4 bv[3];
        #pragma unroll
        for (int c = 0; c < 3; ++c)
            #pragma unroll
            for (int d = 0; d < 4; ++d)
                bv[c][d] = lds_t[bg + c * CPLANE + woff[d]];

        // Phase 1 (r7-verified): wgt[vf][px] = conv + bias
        f32x4 a0 = cbA, a1 = cbB;
        #pragma unroll
        for (int c = 0; c < 3; ++c) {
            f16x8 B = __builtin_bit_cast(f16x8, bv[c]);
            a0 = __builtin_amdgcn_mfma_f32_16x16x32_f16(
                     __builtin_bit_cast(f16x8, afr[c]),     B, a0, 0, 0, 0);
            a1 = __builtin_amdgcn_mfma_f32_16x16x32_f16(
                     __builtin_bit_cast(f16x8, afr[3 + c]), B, a1, 0, 0, 0);
        }

        // In-lane pairs (r7-verified): rows 4s+r -> pairs 2s,2s+1,8+2s,9+2s
        uint32_t wq0 = pack_f16x2(a0[0], a0[1]);
        uint32_t wq1 = pack_f16x2(a0[2], a0[3]);
        uint32_t wq2 = pack_f16x2(a1[0], a1[1]);
        uint32_t wq3 = pack_f16x2(a1[2], a1[3]);

        // b64 writes; slot t=15 (s==3, wq3) is written but never consumed.
        const int pb = (py * 16 + fl) * PTS;
        uint2 w01; w01.x = wq0; w01.y = wq1;
        uint2 w23; w23.x = wq2; w23.y = wq3;
        *reinterpret_cast<uint2*>(&pbuf[pb + 2 * s])     = w01;
        *reinterpret_cast<uint2*>(&pbuf[pb + 8 + 2 * s]) = w23;
    }

    // nb reads HOISTED above the barrier (r13 win): lds_t stable since barrier 1
    const int px  = tid & 15;
    const int py2 = tid >> 4;
    const uint32_t* basep = lds_t + ((px & 1) ? COPYW : 0) + (px >> 1);

    uint32_t nb[45];
    #pragma unroll
    for (int c = 0; c < NC; ++c)
        #pragma unroll
        for (int i = 0; i < KSZ; ++i)
            #pragma unroll
            for (int q = 0; q < 3; ++q)
                nb[c * 15 + i * 3 + q] =
                    basep[c * CPLANE + (py2 + i) * TWRD + q];

    __syncthreads();

    // ---- Phase 2: packed-f16 FMA accumulation (v_pk_fma_f16, full-rate
    // VOP3P). Two f16x2 accumulators per channel (chain depth 8) + f32 combine.
    u32x4 wp4[4];
    const int rb = (py2 * 16 + px) * PTS;
    #pragma unroll
    for (int r = 0; r < 4; ++r)
        wp4[r] = *reinterpret_cast<const u32x4*>(&pbuf[rb + 4 * r]);

    float* ob = out + (size_t)b * NC * NH * NW
                    + (size_t)(bh0 + py2) * NW + (bw0 + px);
    #pragma unroll
    for (int c = 0; c < NC; ++c) {
        // residual: center tap (i=2,j=2) = lo half of pair idx 7 -> init accA.x
        uint32_t accA = nb[c * 15 + 7] & 0xFFFFu;   // (ctr, 0) as f16x2
        uint32_t accB = 0u;
        #pragma unroll
        for (int t = 0; t < 8; ++t)
            asm("v_pk_fma_f16 %0, %1, %2, %0"
                : "+v"(accA)
                : "v"(wp4[t >> 2][t & 3]), "v"(nb[c * 15 + t]));
        #pragma unroll
        for (int t = 8; t < 15; ++t)
            asm("v_pk_fma_f16 %0, %1, %2, %0"
                : "+v"(accB)
                : "v"(wp4[t >> 2][t & 3]), "v"(nb[c * 15 + t]));
        half2v hA = __builtin_bit_cast(half2v, accA);
        half2v hB = __builtin_bit_cast(half2v, accB);
        ob[(size_t)c * NH * NW] =
            ((float)hA.x + (float)hA.y) + ((float)hB.x + (float)hB.y);
    }
}

extern "C" void kernel_launch(void* const* d_in, const int* in_sizes, int n_in,
                              void* d_out, int out_size, void* d_ws, size_t ws_size,
                              hipStream_t stream)
{
    const float* x  = (const float*)d_in[0];
    const float* cw = (const float*)d_in[1];
    const float* cb = (const float*)d_in[2];
    float* out      = (float*)d_out;
    uint32_t* Atab  = (uint32_t*)d_ws;                    // 6144 B
    float*    cbv   = (float*)((char*)d_ws + 6144);       // 128 B

    prep_AB<<<7, 256, 0, stream>>>(cw, cb, Atab, cbv);

    dim3 grid(NBATCH * (NH / TH) * (NW / TW));   // 4096 blocks
    highorder24<<<grid, 256, 0, stream>>>(x, Atab, cbv, out);
}